// Round 1
// baseline (598.694 us; speedup 1.0000x reference)
//
#include <hip/hip_runtime.h>

#define N_NODES 24
#define CH 32

// Each block: one node (blockIdx.y), 256 consecutive samples (blockIdx.x).
// Node-uniform weight pointers -> scalar loads (SMEM pipe), VALU does only FMAs.
__global__ __launch_bounds__(256) void grouped_pnmlp_kernel(
    const float* __restrict__ h,      // [B][24][32]
    const int*   __restrict__ valid,  // [B][24]
    const float* __restrict__ W1,     // [6][4][32][32]
    const float* __restrict__ b1,     // [6][4][32]
    const float* __restrict__ W2,     // [6][4][32]
    const float* __restrict__ b2,     // [6][4]
    float*       __restrict__ out,    // [B][24]
    int n_samples)
{
    const int node = blockIdx.y;

    // node -> (group g, slot k), derived from GROUPING:
    //   g0:[0,3,6,9] g1:[1,4,7,10] g2:[2,5,8,11] g3:[12..15] g4:[16,18,20,22] g5:[17,19,21,23]
    int g, k;
    if (node < 12)      { g = node % 3;               k = node / 3;        }
    else if (node < 16) { g = 3;                      k = node - 12;       }
    else                { g = 4 + ((node - 16) & 1);  k = (node - 16) >> 1; }

    // group-member nodes for validity: vbase + k*vstride
    int vbase, vstride;
    if (g < 3)       { vbase = g;            vstride = 3; }
    else if (g == 3) { vbase = 12;           vstride = 1; }
    else             { vbase = 16 + (g - 4); vstride = 2; }

    const int gk = g * 4 + k;
    const float* __restrict__ w1  = W1 + (size_t)gk * CH * CH;  // [l][j]
    const float* __restrict__ w2  = W2 + (size_t)gk * CH;
    const float* __restrict__ bb1 = b1 + (size_t)gk * CH;
    const float               bb2 = b2[gk];

    const int b = blockIdx.x * blockDim.x + threadIdx.x;
    if (b >= n_samples) return;

    // x = relu(h[b][node][:]) — one 128B line per thread, 8x float4
    const float4* __restrict__ xp =
        (const float4*)(h + ((size_t)b * N_NODES + node) * CH);
    float x[CH];
#pragma unroll
    for (int i = 0; i < 8; ++i) {
        float4 v = xp[i];
        x[4*i+0] = fmaxf(v.x, 0.0f);
        x[4*i+1] = fmaxf(v.y, 0.0f);
        x[4*i+2] = fmaxf(v.z, 0.0f);
        x[4*i+3] = fmaxf(v.w, 0.0f);
    }

    // hid = x @ W1 + b1  (weights wave-uniform -> s_load operands)
    float hid[CH];
#pragma unroll
    for (int j = 0; j < CH; ++j) hid[j] = bb1[j];
#pragma unroll
    for (int l = 0; l < CH; ++l) {
        const float xl = x[l];
#pragma unroll
        for (int j = 0; j < CH; ++j)
            hid[j] = fmaf(xl, w1[l * CH + j], hid[j]);
    }

    // out = relu(hid) @ W2 + b2
    float acc = bb2;
#pragma unroll
    for (int j = 0; j < CH; ++j)
        acc = fmaf(fmaxf(hid[j], 0.0f), w2[j], acc);

    // group validity: any of the 4 member nodes valid
    const int* __restrict__ vrow = valid + (size_t)b * N_NODES;
    const int vs = vrow[vbase] + vrow[vbase + vstride] +
                   vrow[vbase + 2 * vstride] + vrow[vbase + 3 * vstride];

    out[(size_t)b * N_NODES + node] = (vs > 0) ? acc : 0.0f;
}

extern "C" void kernel_launch(void* const* d_in, const int* in_sizes, int n_in,
                              void* d_out, int out_size, void* d_ws, size_t ws_size,
                              hipStream_t stream) {
    const float* h     = (const float*)d_in[0];
    const int*   valid = (const int*)d_in[1];
    const float* W1    = (const float*)d_in[2];
    const float* b1    = (const float*)d_in[3];
    const float* W2    = (const float*)d_in[4];
    const float* b2    = (const float*)d_in[5];
    float* out = (float*)d_out;

    const int n_samples = in_sizes[0] / (N_NODES * CH);

    dim3 block(256, 1, 1);
    dim3 grid((n_samples + 255) / 256, N_NODES, 1);
    grouped_pnmlp_kernel<<<grid, block, 0, stream>>>(h, valid, W1, b1, W2, b2,
                                                     out, n_samples);
}